// Round 1
// baseline (5462.909 us; speedup 1.0000x reference)
//
#include <hip/hip_runtime.h>
#include <hip/hip_bf16.h>

// Problem constants (from reference): T=8192 steps, batch=1, H=21 hidden.
#define T_LEN 8192
#define HDIM  21
#define GDIM  84   // 4*H gate rows

// Workspace layout (floats):
//  zx1[T*84] zx2[T*84] zx3[T*84] h1[T*21] h2[T*21] h3[T*21] M1[84*21] M2[84*21] b3p[84]
//  total ~10.3 MB — assumed <= ws_size.

__device__ __forceinline__ float sigm(float x) {
    // stable: x->-inf: exp(+inf)=inf -> 0 ; x->+inf: exp(-inf)=0 -> 1
    return 1.0f / (1.0f + __expf(-x));
}
__device__ __forceinline__ float tanh_stable(float x) {
    // 1 - 2/(exp(2x)+1): x->+inf: e=inf -> 1 ; x->-inf: e=0 -> -1  (no inf/inf)
    float e = __expf(2.0f * x);
    return 1.0f - 2.0f / (e + 1.0f);
}

// ---------------------------------------------------------------------------
// K1: parallel input projections for LSTM1 and LSTM2.
// in1 = [src0, src2, src3], in2 = [src1, src2, src3]
// zx[t][j] = b[j] + Wih[j,:] . in[t]
// ---------------------------------------------------------------------------
__global__ void zx12_kernel(const float* __restrict__ src,
                            const float* __restrict__ Wih1, const float* __restrict__ b1,
                            const float* __restrict__ Wih2, const float* __restrict__ b2,
                            float* __restrict__ zx1, float* __restrict__ zx2)
{
    int g = blockIdx.x * blockDim.x + threadIdx.x;
    if (g >= T_LEN * GDIM) return;
    int t = g / GDIM, j = g - t * GDIM;
    float s0 = src[t * 4 + 0];
    float s1 = src[t * 4 + 1];
    float s2 = src[t * 4 + 2];
    float s3 = src[t * 4 + 3];
    float z1 = b1[j];
    z1 = __builtin_fmaf(Wih1[j * 3 + 0], s0, z1);
    z1 = __builtin_fmaf(Wih1[j * 3 + 1], s2, z1);
    z1 = __builtin_fmaf(Wih1[j * 3 + 2], s3, z1);
    float z2 = b2[j];
    z2 = __builtin_fmaf(Wih2[j * 3 + 0], s1, z2);
    z2 = __builtin_fmaf(Wih2[j * 3 + 1], s2, z2);
    z2 = __builtin_fmaf(Wih2[j * 3 + 2], s3, z2);
    zx1[g] = z1;
    zx2[g] = z2;
}

// ---------------------------------------------------------------------------
// K2: fold linear layers into LSTM3's input projection.
// M1[j,k] = Wih3[j,0]   * W1[0,k]
// M2[j,k] = sum_m Wih3[j,1+m] * W2[m,k]          (m = 0..48)
// b3p[j]  = b3[j] + Wih3[j,0]*bl1 + sum_m Wih3[j,1+m]*bl2[m]
// ---------------------------------------------------------------------------
__global__ void fold_kernel(const float* __restrict__ Wih3,
                            const float* __restrict__ W1, const float* __restrict__ bl1,
                            const float* __restrict__ W2, const float* __restrict__ bl2,
                            const float* __restrict__ b3,
                            float* __restrict__ M1, float* __restrict__ M2,
                            float* __restrict__ b3p)
{
    int idx = blockIdx.x * blockDim.x + threadIdx.x;
    if (idx < GDIM * HDIM) {
        int j = idx / HDIM, k = idx - j * HDIM;
        M1[idx] = Wih3[j * 50 + 0] * W1[k];
        float s = 0.0f;
        for (int m = 0; m < 49; ++m)
            s = __builtin_fmaf(Wih3[j * 50 + 1 + m], W2[m * HDIM + k], s);
        M2[idx] = s;
    }
    if (idx < GDIM) {
        float s = b3[idx] + Wih3[idx * 50 + 0] * bl1[0];
        for (int m = 0; m < 49; ++m)
            s = __builtin_fmaf(Wih3[idx * 50 + 1 + m], bl2[m], s);
        b3p[idx] = s;
    }
}

// ---------------------------------------------------------------------------
// K3/K5: the sequential LSTM scan. ONE wave per block, zero barriers.
// Row layout (PyTorch gate order i,f,g,o in rows 0..83):
//   lane k   (k<21):  rowA = k      (i, sigmoid)   rowB = 42+k (g, tanh)
//   lane 32+k(k<21):  rowA = 21+k   (f, sigmoid)   rowB = 63+k (o, sigmoid)
// Per step: acc = zx[t][row] + Whh[row,:].h  (42 FMAs/lane, h wave-uniform in
// scalars via v_readlane), activations branchless (tanh = 2*sigm(2x)-1),
// p = sig(i)*tanh(g) on lo lanes, one __shfl_xor(32) moves p to hi lanes,
// c/h updated on hi lanes, h broadcast back with 21 readlanes.
// grid==2 runs two independent LSTMs (blockIdx selects A/B pointer set).
// ---------------------------------------------------------------------------
__global__ __launch_bounds__(64)
void lstm_scan_kernel(const float* __restrict__ zxA, const float* __restrict__ WhhA,
                      float* __restrict__ houtA,
                      const float* __restrict__ zxB, const float* __restrict__ WhhB,
                      float* __restrict__ houtB)
{
    const float* zx  = (blockIdx.x == 0) ? zxA  : zxB;
    const float* Whh = (blockIdx.x == 0) ? WhhA : WhhB;
    float*       hout = (blockIdx.x == 0) ? houtA : houtB;

    const int lane = threadIdx.x;
    const int k = lane & 31;
    const bool hi = lane >= 32;
    const bool act = k < HDIM;
    const int kk = act ? k : 0;

    const int rowA = hi ? (HDIM + kk)     : kk;            // f : i  (both sigmoid)
    const int rowB = hi ? (3 * HDIM + kk) : (2 * HDIM + kk); // o : g
    // vB activation: lo -> tanh via 2*sigm(2x)-1 ; hi -> sigm(x)
    const float sB = hi ? 1.0f : 2.0f;
    const float mB = hi ? 1.0f : 2.0f;
    const float aB = hi ? 0.0f : -1.0f;

    float wa[HDIM], wb[HDIM];
#pragma unroll
    for (int j = 0; j < HDIM; ++j) {
        wa[j] = Whh[rowA * HDIM + j];
        wb[j] = Whh[rowB * HDIM + j];
    }

    float hs[HDIM];
#pragma unroll
    for (int j = 0; j < HDIM; ++j) hs[j] = 0.0f;
    float c = 0.0f;

    // software-pipelined zx prefetch, depth 2
    float za  = zx[rowA],        zb  = zx[rowB];
    float zaN = zx[GDIM + rowA], zbN = zx[GDIM + rowB];

    for (int t = 0; t < T_LEN; ++t) {
        float za2 = 0.0f, zb2 = 0.0f;
        if (t + 2 < T_LEN) {
            za2 = zx[(t + 2) * GDIM + rowA];
            zb2 = zx[(t + 2) * GDIM + rowB];
        }

        float accA = za, accB = zb;
#pragma unroll
        for (int j = 0; j < HDIM; ++j) {
            accA = __builtin_fmaf(wa[j], hs[j], accA);
            accB = __builtin_fmaf(wb[j], hs[j], accB);
        }

        float vA = sigm(accA);                                   // sig(i) | sig(f)
        float vB = __builtin_fmaf(mB, sigm(sB * accB), aB);      // tanh(g) | sig(o)

        float p   = vA * vB;               // lo: sig(i)*tanh(g)
        float pSw = __shfl_xor(p, 32);     // hi lanes receive lo's p

        c = __builtin_fmaf(vA, c, pSw);    // hi: sig(f)*c + sig(i)*tanh(g)
        float th = tanh_stable(c);
        float h  = vB * th;                // hi: sig(o)*tanh(c)

        if (hi && act) hout[t * HDIM + k] = h;

        // broadcast new h (lanes 32..52) to wave-uniform scalars
#pragma unroll
        for (int j = 0; j < HDIM; ++j) {
            hs[j] = __int_as_float(
                __builtin_amdgcn_readlane(__float_as_int(h), 32 + j));
        }

        za = zaN; zb = zbN; zaN = za2; zbN = zb2;
    }
}

// ---------------------------------------------------------------------------
// K4: parallel zx3 from stored h1,h2 and folded M1,M2.
// ---------------------------------------------------------------------------
__global__ void zx3_kernel(const float* __restrict__ h1, const float* __restrict__ h2,
                           const float* __restrict__ M1, const float* __restrict__ M2,
                           const float* __restrict__ b3p, float* __restrict__ zx3)
{
    int g = blockIdx.x * blockDim.x + threadIdx.x;
    if (g >= T_LEN * GDIM) return;
    int t = g / GDIM, j = g - t * GDIM;
    const float* h1t = h1 + t * HDIM;
    const float* h2t = h2 + t * HDIM;
    const float* m1  = M1 + j * HDIM;
    const float* m2  = M2 + j * HDIM;
    float s = b3p[j];
#pragma unroll
    for (int kq = 0; kq < HDIM; ++kq) {
        s = __builtin_fmaf(m1[kq], h1t[kq], s);
        s = __builtin_fmaf(m2[kq], h2t[kq], s);
    }
    zx3[g] = s;
}

// ---------------------------------------------------------------------------
// K6: final linear: out[t] = h3[t] @ W3.T + bl3   (W3: [2,21])
// ---------------------------------------------------------------------------
__global__ void out_kernel(const float* __restrict__ h3, const float* __restrict__ W3,
                           const float* __restrict__ bl3, float* __restrict__ out)
{
    int t = blockIdx.x * blockDim.x + threadIdx.x;
    if (t >= T_LEN) return;
    float s0 = bl3[0], s1 = bl3[1];
#pragma unroll
    for (int kq = 0; kq < HDIM; ++kq) {
        float h = h3[t * HDIM + kq];
        s0 = __builtin_fmaf(W3[kq], h, s0);
        s1 = __builtin_fmaf(W3[HDIM + kq], h, s1);
    }
    out[t * 2 + 0] = s0;
    out[t * 2 + 1] = s1;
}

extern "C" void kernel_launch(void* const* d_in, const int* in_sizes, int n_in,
                              void* d_out, int out_size, void* d_ws, size_t ws_size,
                              hipStream_t stream) {
    const float* src  = (const float*)d_in[0];
    const float* Wih1 = (const float*)d_in[1];
    const float* Whh1 = (const float*)d_in[2];
    const float* b1   = (const float*)d_in[3];
    const float* W1   = (const float*)d_in[4];
    const float* bl1  = (const float*)d_in[5];
    const float* Wih2 = (const float*)d_in[6];
    const float* Whh2 = (const float*)d_in[7];
    const float* b2   = (const float*)d_in[8];
    const float* W2   = (const float*)d_in[9];
    const float* bl2  = (const float*)d_in[10];
    const float* Wih3 = (const float*)d_in[11];
    const float* Whh3 = (const float*)d_in[12];
    const float* b3   = (const float*)d_in[13];
    const float* W3   = (const float*)d_in[14];
    const float* bl3  = (const float*)d_in[15];
    float* out = (float*)d_out;

    float* ws  = (float*)d_ws;
    float* zx1 = ws;
    float* zx2 = zx1 + (size_t)T_LEN * GDIM;
    float* zx3 = zx2 + (size_t)T_LEN * GDIM;
    float* h1  = zx3 + (size_t)T_LEN * GDIM;
    float* h2  = h1  + (size_t)T_LEN * HDIM;
    float* h3  = h2  + (size_t)T_LEN * HDIM;
    float* M1  = h3  + (size_t)T_LEN * HDIM;
    float* M2  = M1  + GDIM * HDIM;
    float* b3p = M2  + GDIM * HDIM;

    zx12_kernel<<<(T_LEN * GDIM + 255) / 256, 256, 0, stream>>>(
        src, Wih1, b1, Wih2, b2, zx1, zx2);
    fold_kernel<<<(GDIM * HDIM + 255) / 256, 256, 0, stream>>>(
        Wih3, W1, bl1, W2, bl2, b3, M1, M2, b3p);
    lstm_scan_kernel<<<2, 64, 0, stream>>>(zx1, Whh1, h1, zx2, Whh2, h2);
    zx3_kernel<<<(T_LEN * GDIM + 255) / 256, 256, 0, stream>>>(
        h1, h2, M1, M2, b3p, zx3);
    lstm_scan_kernel<<<1, 64, 0, stream>>>(zx3, Whh3, h3, zx3, Whh3, h3);
    out_kernel<<<(T_LEN + 255) / 256, 256, 0, stream>>>(h3, W3, bl3, out);
}